// Round 9
// baseline (166.109 us; speedup 1.0000x reference)
//
#include <hip/hip_runtime.h>
#include <stdint.h>

#define SQ 2048
#define DH 128
#define SCALER 0.08838834764831845f  // 1/sqrt(128)

typedef float f32x4 __attribute__((ext_vector_type(4)));
typedef short s16x8 __attribute__((ext_vector_type(8)));
typedef short s16x4 __attribute__((ext_vector_type(4)));

__device__ __forceinline__ short f2bf(float f) {
  uint32_t x = __float_as_uint(f);
  uint32_t r = (x + 0x7fffu + ((x >> 16) & 1u)) >> 16;  // RNE
  return (short)(r & 0xffffu);
}

__device__ __forceinline__ void mfma16(f32x4& d, s16x8 a, s16x8 b) {
  asm("v_mfma_f32_16x16x32_bf16 %0, %1, %2, %0" : "+v"(d) : "v"(a), "v"(b));
}

__device__ __forceinline__ void gload16(const void* g, void* l) {
  __builtin_amdgcn_global_load_lds(
      (__attribute__((address_space(1))) void*)const_cast<void*>(g),
      (__attribute__((address_space(3))) void*)l, 16, 0, 0);
}

// ---------------- f32 -> bf16 convert, 3 sources, contiguous dst ----------------
__global__ __launch_bounds__(256) void cvt3_bf16(
    const float* __restrict__ a, const float* __restrict__ b,
    const float* __restrict__ c, short* __restrict__ out,
    int na8, int nb8, int nc8) {
  int i = blockIdx.x * 256 + threadIdx.x;
  if (i >= na8 + nb8 + nc8) return;
  const float* src;
  if (i < na8) src = a + (size_t)i * 8;
  else if (i < na8 + nb8) src = b + (size_t)(i - na8) * 8;
  else src = c + (size_t)(i - na8 - nb8) * 8;
  const float4* p = (const float4*)src;
  float4 u = p[0], v = p[1];
  s16x8 o;
  o[0] = f2bf(u.x); o[1] = f2bf(u.y); o[2] = f2bf(u.z); o[3] = f2bf(u.w);
  o[4] = f2bf(v.x); o[5] = f2bf(v.y); o[6] = f2bf(v.z); o[7] = f2bf(v.w);
  *((s16x8*)out + i) = o;
}

// ---------------- GEMM: C[M][N] = A[M][K] * B[N][K]^T + bias ----------------
// Tile 128(M) x 64(N), BK=64, 4 waves (2Mx2N), wave-tile 64x32.
// MODE 0: plain f32 C write.  MODE 1: fused RoPE+split epilogue (QKV proj).
template <int MODE>
__global__ __launch_bounds__(256) void gemm_bt_bias(
    const short* __restrict__ A, const short* __restrict__ B,
    const float* __restrict__ bias, float* __restrict__ C,
    const float* __restrict__ pe, short* __restrict__ qws,
    short* __restrict__ kws, short* __restrict__ vtws,
    int M, int N, int K) {
  __shared__ __align__(16) short smem[128 * 64 + 64 * 64];  // As | Bs (24 KB)
  short* As = smem;             // [128][64]
  short* Bs = smem + 128 * 64;  // [64][64]
  const int t = threadIdx.x;
  const int l = t & 63, w = t >> 6;
  const int wr = w >> 1, wc = w & 1;
  const int lr = l & 15, lk = l >> 4;
  const int m0 = blockIdx.y * 128, n0 = blockIdx.x * 64;

  f32x4 acc[4][2] = {};

  for (int kt = 0; kt < K; kt += 64) {
    const short* ga = A + (size_t)m0 * K + kt;
    const short* gb = B + (size_t)n0 * K + kt;
#pragma unroll
    for (int i = 0; i < 4; ++i) {
      int j = i * 256 + t;                       // A chunk id, 0..1023
      int lbase = (i * 256 + (t & ~63)) << 4;
      gload16(ga + (size_t)(j >> 3) * K + ((j & 7) << 3), (char*)As + lbase);
    }
#pragma unroll
    for (int i = 0; i < 2; ++i) {
      int j = i * 256 + t;                       // B chunk id, 0..511
      int lbase = (i * 256 + (t & ~63)) << 4;
      gload16(gb + (size_t)(j >> 3) * K + ((j & 7) << 3), (char*)Bs + lbase);
    }
    __syncthreads();
#pragma unroll
    for (int ks = 0; ks < 2; ++ks) {
      s16x8 af[4], bg[2];
#pragma unroll
      for (int i = 0; i < 4; ++i)
        af[i] = *(const s16x8*)(As + (wr * 64 + i * 16 + lr) * 64 + ks * 32 + lk * 8);
#pragma unroll
      for (int i = 0; i < 2; ++i)
        bg[i] = *(const s16x8*)(Bs + (wc * 32 + i * 16 + lr) * 64 + ks * 32 + lk * 8);
#pragma unroll
      for (int mi = 0; mi < 4; ++mi)
#pragma unroll
        for (int ni = 0; ni < 2; ++ni)
          mfma16(acc[mi][ni], af[mi], bg[ni]);
    }
    __syncthreads();
  }

  if (MODE == 0) {
#pragma unroll
    for (int mi = 0; mi < 4; ++mi) {
      int row = m0 + wr * 64 + mi * 16 + lk * 4;
#pragma unroll
      for (int ni = 0; ni < 2; ++ni) {
        int col = n0 + wc * 32 + ni * 16 + lr;
        float bv = bias[col];
#pragma unroll
        for (int r = 0; r < 4; ++r)
          C[(size_t)(row + r) * N + col] = acc[mi][ni][r] + bv;
      }
    }
  } else {
    // ---- rope in-register, re-layout through LDS, coalesced stores ----
    if (n0 < 2304) {  // Q or K: Ct s-major [128][72]
      short* Ct = smem;
#pragma unroll
      for (int mi = 0; mi < 4; ++mi) {
        int row_l = wr * 64 + mi * 16 + lk * 4;
#pragma unroll
        for (int ni = 0; ni < 2; ++ni) {
          int col_l = wc * 32 + ni * 16 + lr;
          int col = n0 + col_l;
          float bv = bias[col];
          int d = col & 127;
#pragma unroll
          for (int r = 0; r < 4; ++r) {
            float v = acc[mi][ni][r] + bv;
            float p = __shfl_xor(v, 1);
            int s = m0 + row_l + r;
            const float* per = pe + (size_t)s * 256;
            float y = v * per[d] + p * per[128 + d];
            if (n0 < 2048) y *= SCALER;
            Ct[(row_l + r) * 72 + col_l] = f2bf(y);
          }
        }
      }
      __syncthreads();
      if (n0 < 2048) {  // Q: [hq][s][128] linear
        int hq = n0 >> 7, d0 = n0 & 127;
#pragma unroll
        for (int i = 0; i < 4; ++i) {
          int idx = i * 256 + t;       // 1024 chunks: 128 s x 8 d-chunks
          int sl = idx >> 3, c = idx & 7;
          s16x8 val = *(const s16x8*)(Ct + sl * 72 + c * 8);
          *(s16x8*)(qws + ((size_t)hq * SQ + m0 + sl) * DH + d0 + c * 8) = val;
        }
      } else {          // K: swizzled slots within 128-d row (round-5 formula)
        int hk = (n0 - 2048) >> 7, d0 = (n0 - 2048) & 127;
#pragma unroll
        for (int i = 0; i < 4; ++i) {
          int idx = i * 256 + t;
          int sl = idx >> 3, c = idx & 7;
          s16x8 val = *(const s16x8*)(Ct + sl * 72 + c * 8);
          int slot = ((d0 >> 3) + c) ^ (sl & 15);
          *(s16x8*)(kws + (size_t)hk * SQ * DH + (size_t)(m0 + sl) * DH + slot * 8) = val;
        }
      }
    } else {  // V: Ct d-major [64][136]
      short* Ct = smem;
      int hk = (n0 - 2304) >> 7, d0 = (n0 - 2304) & 127;
#pragma unroll
      for (int mi = 0; mi < 4; ++mi) {
        int row_l = wr * 64 + mi * 16 + lk * 4;
#pragma unroll
        for (int ni = 0; ni < 2; ++ni) {
          int col_l = wc * 32 + ni * 16 + lr;
          float bv = bias[n0 + col_l];
#pragma unroll
          for (int r = 0; r < 4; ++r)
            Ct[col_l * 136 + row_l + r] = f2bf(acc[mi][ni][r] + bv);
        }
      }
      __syncthreads();
#pragma unroll
      for (int i = 0; i < 4; ++i) {
        int idx = i * 256 + t;         // 1024 chunks: 64 d x 16 s-chunks
        int dl = idx >> 4, c = idx & 15;
        s16x8 val = *(const s16x8*)(Ct + dl * 136 + c * 8);
        int d = d0 + dl;
        size_t dst = (size_t)hk * DH * SQ + (size_t)d * SQ +
                     (size_t)((m0 >> 6) + (c >> 3)) * 64 +
                     (size_t)(((c & 7) ^ (d & 7)) << 3);
        *(s16x8*)(vtws + dst) = val;
      }
    }
  }
}

// ---------------- Flash attention (swapped QK^T; 2 waves x 32 q-rows) ----------------
// 512 WGs: (h, qb), balanced pairing. QBLK=64, KBLK=64, double-buffered.
// Each wave owns 32 q-rows (2 B-frags): every K/V fragment read feeds 2 MFMAs,
// halving per-q LDS traffic (the round-8 bottleneck).
__global__ __launch_bounds__(128) void attn_fwd(
    const short* __restrict__ qws, const short* __restrict__ kws,
    const short* __restrict__ vtws, short* __restrict__ attnws) {
  __shared__ __align__(16) short Ks[2][64 * 128];  // [buf][krow][d], slots swizzled
  __shared__ __align__(16) short Vt[2][128 * 64];  // [buf][d][kcol], slots swizzled
  __shared__ __align__(16) short Ps[2][32 * 72];   // per-wave P [q=qt*16+lr][64k]

  const int bx = blockIdx.x;
  const int h = bx & 15;
  const int i_ = bx >> 4;
  const int qb = (i_ < 16) ? (31 - i_) : (i_ - 16);  // balanced pairing
  const int hk = h >> 3;
  const int t = threadIdx.x, l = t & 63, w = t >> 6;  // w in {0,1}
  const int lr = l & 15, lk = l >> 4;

  // Q fragments: lane holds Q[q = qt*16+lr][d-slice], rows qb*64 + w*32 + ...
  s16x8 qf[2][4];
  {
    const short* qbase = qws + ((size_t)h * SQ + (size_t)qb * 64 + w * 32) * DH;
#pragma unroll
    for (int qt = 0; qt < 2; ++qt)
#pragma unroll
      for (int kd = 0; kd < 4; ++kd)
        qf[qt][kd] = *(const s16x8*)(qbase + (size_t)(qt * 16 + lr) * DH + kd * 32 + lk * 8);
  }

  f32x4 o[2][8] = {};
  float m_[2] = {-1e30f, -1e30f}, l_[2] = {0.f, 0.f};

  const short* gkh = kws + (size_t)hk * SQ * DH;
  const short* gvh = vtws + (size_t)hk * DH * SQ;

#define STAGE(buf, kb)                                                          \
  {                                                                             \
    const short* gk = gkh + (size_t)(kb)*64 * DH;                               \
    const short* gv = gvh + (size_t)(kb)*64;                                    \
    _Pragma("unroll") for (int i = 0; i < 8; ++i) {                             \
      int j = i * 128 + t;                                                      \
      int lbase = (i * 128 + (t & ~63)) << 4;                                   \
      gload16(gk + (size_t)(j >> 4) * DH + ((j & 15) << 3),                     \
              (char*)Ks[buf] + lbase);                                          \
      gload16(gv + (size_t)(j >> 3) * SQ + ((j & 7) << 3),                      \
              (char*)Vt[buf] + lbase);                                          \
    }                                                                           \
  }

  STAGE(0, 0);
  __syncthreads();

  for (int kb = 0; kb <= qb; ++kb) {
    const int cur = kb & 1;
    if (kb < qb) STAGE(cur ^ 1, kb + 1);  // prefetch next tile under compute

    // ---- S^T = K Q^T : lane gets S[q = qt*16+lr][k = nt*16 + lk*4 + r] ----
    f32x4 sc_[2][4] = {};
#pragma unroll
    for (int kd = 0; kd < 4; ++kd) {
#pragma unroll
      for (int nt = 0; nt < 4; ++nt) {
        int krow = nt * 16 + lr;
        int slot = (kd * 4 + lk) ^ lr;
        s16x8 kf = *(const s16x8*)(Ks[cur] + krow * 128 + slot * 8);
        mfma16(sc_[0][nt], kf, qf[0][kd]);
        mfma16(sc_[1][nt], kf, qf[1][kd]);
      }
    }
    // ---- causal mask (diagonal k-block only) ----
    if (kb == qb) {
#pragma unroll
      for (int qt = 0; qt < 2; ++qt) {
        int qloc = w * 32 + qt * 16 + lr;
#pragma unroll
        for (int nt = 0; nt < 4; ++nt)
#pragma unroll
          for (int r = 0; r < 4; ++r) {
            int col = nt * 16 + lk * 4 + r;
            if (col > qloc) sc_[qt][nt][r] = -1e30f;
          }
      }
    }
    // ---- online softmax per q-tile: in-lane over 16, then 2 shuffles ----
#pragma unroll
    for (int qt = 0; qt < 2; ++qt) {
      float rm = -1e30f;
#pragma unroll
      for (int nt = 0; nt < 4; ++nt)
        rm = fmaxf(rm, fmaxf(fmaxf(sc_[qt][nt][0], sc_[qt][nt][1]),
                             fmaxf(sc_[qt][nt][2], sc_[qt][nt][3])));
      rm = fmaxf(rm, __shfl_xor(rm, 16));
      rm = fmaxf(rm, __shfl_xor(rm, 32));
      float mn = fmaxf(m_[qt], rm);
      float scl = __expf(m_[qt] - mn);
      float rs = 0.f;
#pragma unroll
      for (int nt = 0; nt < 4; ++nt)
#pragma unroll
        for (int r = 0; r < 4; ++r) {
          sc_[qt][nt][r] = __expf(sc_[qt][nt][r] - mn);
          rs += sc_[qt][nt][r];
        }
      rs += __shfl_xor(rs, 16);
      rs += __shfl_xor(rs, 32);
      l_[qt] = l_[qt] * scl + rs;
      m_[qt] = mn;
#pragma unroll
      for (int dt = 0; dt < 8; ++dt)
#pragma unroll
        for (int r = 0; r < 4; ++r) o[qt][dt][r] *= scl;
      // P -> per-wave LDS (row q = qt*16+lr)
      short* ps = (short*)Ps[w];
#pragma unroll
      for (int nt = 0; nt < 4; ++nt)
#pragma unroll
        for (int r = 0; r < 4; ++r)
          ps[(qt * 16 + lr) * 72 + nt * 16 + lk * 4 + r] = f2bf(sc_[qt][nt][r]);
    }
    // ---- O^T += V^T P^T : each V fragment feeds both q-tiles ----
    {
      const short* ps = (const short*)Ps[w];
#pragma unroll
      for (int kp = 0; kp < 2; ++kp) {
        s16x8 pb0 = *(const s16x8*)(ps + lr * 72 + kp * 32 + lk * 8);
        s16x8 pb1 = *(const s16x8*)(ps + (16 + lr) * 72 + kp * 32 + lk * 8);
#pragma unroll
        for (int dt = 0; dt < 8; ++dt) {
          int drow = dt * 16 + lr;
          int slot = (kp * 4 + lk) ^ (lr & 7);
          s16x8 vb = *(const s16x8*)(Vt[cur] + drow * 64 + slot * 8);
          mfma16(o[0][dt], vb, pb0);
          mfma16(o[1][dt], vb, pb1);
        }
      }
    }
    __syncthreads();
  }
#undef STAGE

  // ---- epilogue: o[qt][dt][r] = O[q = qb*64+w*32+qt*16+lr][d = dt*16+lk*4+r] ----
#pragma unroll
  for (int qt = 0; qt < 2; ++qt) {
    int srow = qb * 64 + w * 32 + qt * 16 + lr;
#pragma unroll
    for (int dt = 0; dt < 8; ++dt) {
      s16x4 st;
#pragma unroll
      for (int r = 0; r < 4; ++r) st[r] = f2bf(o[qt][dt][r] / l_[qt]);
      *(s16x4*)(attnws + (size_t)srow * 2048 + h * DH + dt * 16 + lk * 4) = st;
    }
  }
}

extern "C" void kernel_launch(void* const* d_in, const int* in_sizes, int n_in,
                              void* d_out, int out_size, void* d_ws, size_t ws_size,
                              hipStream_t stream) {
  (void)in_sizes; (void)n_in; (void)out_size; (void)ws_size;
  const float* x     = (const float*)d_in[0];
  const float* w_qkv = (const float*)d_in[2];
  const float* b_qkv = (const float*)d_in[3];
  const float* w_o   = (const float*)d_in[4];
  const float* b_o   = (const float*)d_in[5];
  const float* pe    = (const float*)d_in[6];
  float* out = (float*)d_out;

  short* xb     = (short*)d_ws;                        // bf16 [2048][2048]
  short* wqkvb  = xb + (size_t)2048 * 2048;            // bf16 [2560][2048]
  short* wob    = wqkvb + (size_t)2560 * 2048;         // bf16 [2048][2048]
  short* qws    = wob + (size_t)2048 * 2048;           // bf16 [16][2048][128]
  short* kws    = qws + (size_t)16 * 2048 * 128;       // bf16 [2][2048][128] swizzled
  short* vtws   = kws + (size_t)2 * 2048 * 128;        // bf16 [2][128][2048] swizzled
  short* attnws = vtws + (size_t)2 * 128 * 2048;       // bf16 [2048][2048]

  cvt3_bf16<<<6656, 256, 0, stream>>>(x, w_qkv, w_o, xb,
                                      2048 * 2048 / 8, 2560 * 2048 / 8, 2048 * 2048 / 8);
  gemm_bt_bias<1><<<dim3(2560 / 64, 2048 / 128), 256, 0, stream>>>(
      xb, wqkvb, b_qkv, nullptr, pe, qws, kws, vtws, 2048, 2560, 2048);
  attn_fwd<<<512, 128, 0, stream>>>(qws, kws, vtws, attnws);
  gemm_bt_bias<0><<<dim3(2048 / 64, 2048 / 128), 256, 0, stream>>>(
      attnws, wob, b_o, out, nullptr, nullptr, nullptr, nullptr, 2048, 2048, 2048);
}

// Round 10
// 149.044 us; speedup vs baseline: 1.1145x; 1.1145x over previous
//
#include <hip/hip_runtime.h>
#include <stdint.h>

#define SQ 2048
#define DH 128
#define SCALER 0.08838834764831845f  // 1/sqrt(128)

typedef float f32x4 __attribute__((ext_vector_type(4)));
typedef short s16x8 __attribute__((ext_vector_type(8)));
typedef short s16x4 __attribute__((ext_vector_type(4)));

__device__ __forceinline__ short f2bf(float f) {
  uint32_t x = __float_as_uint(f);
  uint32_t r = (x + 0x7fffu + ((x >> 16) & 1u)) >> 16;  // RNE
  return (short)(r & 0xffffu);
}

__device__ __forceinline__ void mfma16(f32x4& d, s16x8 a, s16x8 b) {
  asm("v_mfma_f32_16x16x32_bf16 %0, %1, %2, %0" : "+v"(d) : "v"(a), "v"(b));
}

__device__ __forceinline__ void gload16(const void* g, void* l) {
  __builtin_amdgcn_global_load_lds(
      (__attribute__((address_space(1))) void*)const_cast<void*>(g),
      (__attribute__((address_space(3))) void*)l, 16, 0, 0);
}

// ---------------- f32 -> bf16 convert, 3 sources, contiguous dst ----------------
__global__ __launch_bounds__(256) void cvt3_bf16(
    const float* __restrict__ a, const float* __restrict__ b,
    const float* __restrict__ c, short* __restrict__ out,
    int na8, int nb8, int nc8) {
  int i = blockIdx.x * 256 + threadIdx.x;
  if (i >= na8 + nb8 + nc8) return;
  const float* src;
  if (i < na8) src = a + (size_t)i * 8;
  else if (i < na8 + nb8) src = b + (size_t)(i - na8) * 8;
  else src = c + (size_t)(i - na8 - nb8) * 8;
  const float4* p = (const float4*)src;
  float4 u = p[0], v = p[1];
  s16x8 o;
  o[0] = f2bf(u.x); o[1] = f2bf(u.y); o[2] = f2bf(u.z); o[3] = f2bf(u.w);
  o[4] = f2bf(v.x); o[5] = f2bf(v.y); o[6] = f2bf(v.z); o[7] = f2bf(v.w);
  *((s16x8*)out + i) = o;
}

// ---------------- GEMM: C[M][N] = A[M][K] * B[N][K]^T + bias ----------------
// Tile 128(M) x 64(N), BK=64, 4 waves (2Mx2N), wave-tile 64x32.
// Double-buffered LDS, 2-phase pipeline (stage next || compute cur, 1 barrier).
// MODE 0: plain f32 C write.  MODE 1: fused RoPE+split epilogue (QKV proj).
template <int MODE>
__global__ __launch_bounds__(256) void gemm_bt_bias(
    const short* __restrict__ A, const short* __restrict__ B,
    const float* __restrict__ bias, float* __restrict__ C,
    const float* __restrict__ pe, short* __restrict__ qws,
    short* __restrict__ kws, short* __restrict__ vtws,
    int M, int N, int K) {
  __shared__ __align__(16) short As_[2][128 * 64];  // 32 KB
  __shared__ __align__(16) short Bs_[2][64 * 64];   // 16 KB
  const int t = threadIdx.x;
  const int l = t & 63, w = t >> 6;
  const int wr = w >> 1, wc = w & 1;
  const int lr = l & 15, lk = l >> 4;
  const int m0 = blockIdx.y * 128, n0 = blockIdx.x * 64;

  f32x4 acc[4][2] = {};

#define GSTAGE(buf, kt)                                                         \
  {                                                                             \
    const short* ga = A + (size_t)m0 * K + (kt);                                \
    const short* gb = B + (size_t)n0 * K + (kt);                                \
    _Pragma("unroll") for (int i = 0; i < 4; ++i) {                             \
      int j = i * 256 + t;                                                      \
      int lbase = (i * 256 + (t & ~63)) << 4;                                   \
      gload16(ga + (size_t)(j >> 3) * K + ((j & 7) << 3),                       \
              (char*)As_[buf] + lbase);                                         \
    }                                                                           \
    _Pragma("unroll") for (int i = 0; i < 2; ++i) {                             \
      int j = i * 256 + t;                                                      \
      int lbase = (i * 256 + (t & ~63)) << 4;                                   \
      gload16(gb + (size_t)(j >> 3) * K + ((j & 7) << 3),                       \
              (char*)Bs_[buf] + lbase);                                         \
    }                                                                           \
  }

  GSTAGE(0, 0);
  __syncthreads();

  const int nk = K >> 6;
  for (int ki = 0; ki < nk; ++ki) {
    const int cur = ki & 1;
    if (ki + 1 < nk) GSTAGE(cur ^ 1, (ki + 1) << 6);  // prefetch under compute
    const short* As = As_[cur];
    const short* Bs = Bs_[cur];
#pragma unroll
    for (int ks = 0; ks < 2; ++ks) {
      s16x8 af[4], bg[2];
#pragma unroll
      for (int i = 0; i < 4; ++i)
        af[i] = *(const s16x8*)(As + (wr * 64 + i * 16 + lr) * 64 + ks * 32 + lk * 8);
#pragma unroll
      for (int i = 0; i < 2; ++i)
        bg[i] = *(const s16x8*)(Bs + (wc * 32 + i * 16 + lr) * 64 + ks * 32 + lk * 8);
#pragma unroll
      for (int mi = 0; mi < 4; ++mi)
#pragma unroll
        for (int ni = 0; ni < 2; ++ni)
          mfma16(acc[mi][ni], af[mi], bg[ni]);
    }
    __syncthreads();  // drains prefetch (vmcnt0) + guards buf reuse
  }
#undef GSTAGE

  if (MODE == 0) {
#pragma unroll
    for (int mi = 0; mi < 4; ++mi) {
      int row = m0 + wr * 64 + mi * 16 + lk * 4;
#pragma unroll
      for (int ni = 0; ni < 2; ++ni) {
        int col = n0 + wc * 32 + ni * 16 + lr;
        float bv = bias[col];
#pragma unroll
        for (int r = 0; r < 4; ++r)
          C[(size_t)(row + r) * N + col] = acc[mi][ni][r] + bv;
      }
    }
  } else {
    short* Ct = (short*)As_;  // re-layout scratch (all waves past final barrier)
    // ---- rope in-register, re-layout through LDS, coalesced stores ----
    if (n0 < 2304) {  // Q or K: Ct s-major [128][72]
#pragma unroll
      for (int mi = 0; mi < 4; ++mi) {
        int row_l = wr * 64 + mi * 16 + lk * 4;
#pragma unroll
        for (int ni = 0; ni < 2; ++ni) {
          int col_l = wc * 32 + ni * 16 + lr;
          int col = n0 + col_l;
          float bv = bias[col];
          int d = col & 127;
#pragma unroll
          for (int r = 0; r < 4; ++r) {
            float v = acc[mi][ni][r] + bv;
            float p = __shfl_xor(v, 1);
            int s = m0 + row_l + r;
            const float* per = pe + (size_t)s * 256;
            float y = v * per[d] + p * per[128 + d];
            if (n0 < 2048) y *= SCALER;
            Ct[(row_l + r) * 72 + col_l] = f2bf(y);
          }
        }
      }
      __syncthreads();
      if (n0 < 2048) {  // Q: [hq][s][128] linear
        int hq = n0 >> 7, d0 = n0 & 127;
#pragma unroll
        for (int i = 0; i < 4; ++i) {
          int idx = i * 256 + t;       // 1024 chunks: 128 s x 8 d-chunks
          int sl = idx >> 3, c = idx & 7;
          s16x8 val = *(const s16x8*)(Ct + sl * 72 + c * 8);
          *(s16x8*)(qws + ((size_t)hq * SQ + m0 + sl) * DH + d0 + c * 8) = val;
        }
      } else {          // K: swizzled slots within 128-d row
        int hk = (n0 - 2048) >> 7, d0 = (n0 - 2048) & 127;
#pragma unroll
        for (int i = 0; i < 4; ++i) {
          int idx = i * 256 + t;
          int sl = idx >> 3, c = idx & 7;
          s16x8 val = *(const s16x8*)(Ct + sl * 72 + c * 8);
          int slot = ((d0 >> 3) + c) ^ (sl & 15);
          *(s16x8*)(kws + (size_t)hk * SQ * DH + (size_t)(m0 + sl) * DH + slot * 8) = val;
        }
      }
    } else {  // V: Ct d-major [64][136]
      int hk = (n0 - 2304) >> 7, d0 = (n0 - 2304) & 127;
#pragma unroll
      for (int mi = 0; mi < 4; ++mi) {
        int row_l = wr * 64 + mi * 16 + lk * 4;
#pragma unroll
        for (int ni = 0; ni < 2; ++ni) {
          int col_l = wc * 32 + ni * 16 + lr;
          float bv = bias[n0 + col_l];
#pragma unroll
          for (int r = 0; r < 4; ++r)
            Ct[col_l * 136 + row_l + r] = f2bf(acc[mi][ni][r] + bv);
        }
      }
      __syncthreads();
#pragma unroll
      for (int i = 0; i < 4; ++i) {
        int idx = i * 256 + t;         // 1024 chunks: 64 d x 16 s-chunks
        int dl = idx >> 4, c = idx & 15;
        s16x8 val = *(const s16x8*)(Ct + dl * 136 + c * 8);
        int d = d0 + dl;
        size_t dst = (size_t)hk * DH * SQ + (size_t)d * SQ +
                     (size_t)((m0 >> 6) + (c >> 3)) * 64 +
                     (size_t)(((c & 7) ^ (d & 7)) << 3);
        *(s16x8*)(vtws + dst) = val;
      }
    }
  }
}

// ---------------- Flash attention (round-8 proven: swapped QK^T, 4w x 16q) ----------------
__global__ __launch_bounds__(256) void attn_fwd(
    const short* __restrict__ qws, const short* __restrict__ kws,
    const short* __restrict__ vtws, short* __restrict__ attnws) {
  __shared__ __align__(16) short Ks[2][64 * 128];  // [buf][krow][d], slots swizzled
  __shared__ __align__(16) short Vt[2][128 * 64];  // [buf][d][kcol], slots swizzled
  __shared__ __align__(16) short Ps[4][16 * 72];   // per-wave P [q=lr][64k], pad 72

  const int bx = blockIdx.x;
  const int h = bx & 15;
  const int i_ = bx >> 4;
  const int qb = (i_ < 16) ? (31 - i_) : (i_ - 16);  // balanced pairing
  const int hk = h >> 3;
  const int t = threadIdx.x, l = t & 63, w = t >> 6;
  const int lr = l & 15, lk = l >> 4;

  s16x8 qf[4];
  {
    const short* qbase = qws + ((size_t)h * SQ + (size_t)qb * 64 + w * 16) * DH;
#pragma unroll
    for (int kd = 0; kd < 4; ++kd)
      qf[kd] = *(const s16x8*)(qbase + (size_t)lr * DH + kd * 32 + lk * 8);
  }

  f32x4 o[8] = {};
  float m_ = -1e30f, l_ = 0.f;

  const short* gkh = kws + (size_t)hk * SQ * DH;
  const short* gvh = vtws + (size_t)hk * DH * SQ;

#define STAGE(buf, kb)                                                          \
  {                                                                             \
    const short* gk = gkh + (size_t)(kb)*64 * DH;                               \
    const short* gv = gvh + (size_t)(kb)*64;                                    \
    _Pragma("unroll") for (int i = 0; i < 4; ++i) {                             \
      int j = i * 256 + t;                                                      \
      int lbase = (i * 256 + (t & ~63)) << 4;                                   \
      gload16(gk + (size_t)(j >> 4) * DH + ((j & 15) << 3),                     \
              (char*)Ks[buf] + lbase);                                          \
      gload16(gv + (size_t)(j >> 3) * SQ + ((j & 7) << 3),                      \
              (char*)Vt[buf] + lbase);                                          \
    }                                                                           \
  }

  STAGE(0, 0);
  __syncthreads();

  for (int kb = 0; kb <= qb; ++kb) {
    const int cur = kb & 1;
    if (kb < qb) STAGE(cur ^ 1, kb + 1);  // prefetch next tile under compute

    // ---- S^T = K Q^T : lane gets S[q=lr][col = nt*16 + lk*4 + r] ----
    f32x4 sc_[4] = {};
#pragma unroll
    for (int kd = 0; kd < 4; ++kd) {
#pragma unroll
      for (int nt = 0; nt < 4; ++nt) {
        int krow = nt * 16 + lr;
        int slot = (kd * 4 + lk) ^ lr;
        s16x8 kf = *(const s16x8*)(Ks[cur] + krow * 128 + slot * 8);
        mfma16(sc_[nt], kf, qf[kd]);
      }
    }
    // ---- causal mask (diagonal k-block only) ----
    if (kb == qb) {
      int qloc = w * 16 + lr;
#pragma unroll
      for (int nt = 0; nt < 4; ++nt)
#pragma unroll
        for (int r = 0; r < 4; ++r) {
          int col = nt * 16 + lk * 4 + r;
          if (col > qloc) sc_[nt][r] = -1e30f;
        }
    }
    // ---- online softmax: in-lane over 16, then 2 shuffles ----
    {
      float rm = -1e30f;
#pragma unroll
      for (int nt = 0; nt < 4; ++nt)
        rm = fmaxf(rm, fmaxf(fmaxf(sc_[nt][0], sc_[nt][1]),
                             fmaxf(sc_[nt][2], sc_[nt][3])));
      rm = fmaxf(rm, __shfl_xor(rm, 16));
      rm = fmaxf(rm, __shfl_xor(rm, 32));
      float mn = fmaxf(m_, rm);
      float scl = __expf(m_ - mn);
      float rs = 0.f;
#pragma unroll
      for (int nt = 0; nt < 4; ++nt)
#pragma unroll
        for (int r = 0; r < 4; ++r) {
          sc_[nt][r] = __expf(sc_[nt][r] - mn);
          rs += sc_[nt][r];
        }
      rs += __shfl_xor(rs, 16);
      rs += __shfl_xor(rs, 32);
      l_ = l_ * scl + rs;
      m_ = mn;
#pragma unroll
      for (int dt = 0; dt < 8; ++dt)
#pragma unroll
        for (int r = 0; r < 4; ++r) o[dt][r] *= scl;
    }
    // ---- P -> per-wave LDS (row q=lr, col = nt*16 + lk*4 + r) ----
    {
      short* ps = (short*)Ps[w];
#pragma unroll
      for (int nt = 0; nt < 4; ++nt)
#pragma unroll
        for (int r = 0; r < 4; ++r)
          ps[lr * 72 + nt * 16 + lk * 4 + r] = f2bf(sc_[nt][r]);
    }
    // ---- O^T += V^T P^T : A = Vt row-frag, B = P from LDS ----
    {
      const short* ps = (const short*)Ps[w];
#pragma unroll
      for (int kp = 0; kp < 2; ++kp) {
        s16x8 pbf = *(const s16x8*)(ps + lr * 72 + kp * 32 + lk * 8);
#pragma unroll
        for (int dt = 0; dt < 8; ++dt) {
          int drow = dt * 16 + lr;
          int slot = (kp * 4 + lk) ^ (lr & 7);
          s16x8 vb = *(const s16x8*)(Vt[cur] + drow * 64 + slot * 8);
          mfma16(o[dt], vb, pbf);
        }
      }
    }
    __syncthreads();
  }
#undef STAGE

  // ---- epilogue: lane owns q-row lr; o[dt][r] = O[q][d=dt*16+lk*4+r] ----
  {
    int srow = qb * 64 + w * 16 + lr;
#pragma unroll
    for (int dt = 0; dt < 8; ++dt) {
      s16x4 st;
#pragma unroll
      for (int r = 0; r < 4; ++r) st[r] = f2bf(o[dt][r] / l_);
      *(s16x4*)(attnws + (size_t)srow * 2048 + h * DH + dt * 16 + lk * 4) = st;
    }
  }
}

extern "C" void kernel_launch(void* const* d_in, const int* in_sizes, int n_in,
                              void* d_out, int out_size, void* d_ws, size_t ws_size,
                              hipStream_t stream) {
  (void)in_sizes; (void)n_in; (void)out_size; (void)ws_size;
  const float* x     = (const float*)d_in[0];
  const float* w_qkv = (const float*)d_in[2];
  const float* b_qkv = (const float*)d_in[3];
  const float* w_o   = (const float*)d_in[4];
  const float* b_o   = (const float*)d_in[5];
  const float* pe    = (const float*)d_in[6];
  float* out = (float*)d_out;

  short* xb     = (short*)d_ws;                        // bf16 [2048][2048]
  short* wqkvb  = xb + (size_t)2048 * 2048;            // bf16 [2560][2048]
  short* wob    = wqkvb + (size_t)2560 * 2048;         // bf16 [2048][2048]
  short* qws    = wob + (size_t)2048 * 2048;           // bf16 [16][2048][128]
  short* kws    = qws + (size_t)16 * 2048 * 128;       // bf16 [2][2048][128] swizzled
  short* vtws   = kws + (size_t)2 * 2048 * 128;        // bf16 [2][128][2048] swizzled
  short* attnws = vtws + (size_t)2 * 128 * 2048;       // bf16 [2048][2048]

  cvt3_bf16<<<6656, 256, 0, stream>>>(x, w_qkv, w_o, xb,
                                      2048 * 2048 / 8, 2560 * 2048 / 8, 2048 * 2048 / 8);
  gemm_bt_bias<1><<<dim3(2560 / 64, 2048 / 128), 256, 0, stream>>>(
      xb, wqkvb, b_qkv, nullptr, pe, qws, kws, vtws, 2048, 2560, 2048);
  attn_fwd<<<512, 256, 0, stream>>>(qws, kws, vtws, attnws);
  gemm_bt_bias<0><<<dim3(2048 / 64, 2048 / 128), 256, 0, stream>>>(
      attnws, wob, b_o, out, nullptr, nullptr, nullptr, nullptr, 2048, 2048, 2048);
}